// Round 18
// baseline (682.341 us; speedup 1.0000x reference)
//
#include <hip/hip_runtime.h>
#include <hip/hip_bf16.h>
#include <cstdint>
#include <cstddef>

// ---------------- problem constants ----------------
#define NB     8
#define NLOC   5000
#define NPTS   40000      // NB*NLOC
#define DIN    26
#define DH     256
#define NBINS  50
#define BSZ    100
#define KNN    16
#define KP     104        // keys row pitch (f64)

// ---------------- workspace layout (bytes), total 214,560,000 ----------------
static const size_t OFF_BHI0  = 40960000;
static const size_t OFF_BLO0  = 41353216;
static const size_t OFF_BDHI0 = 41746432;
static const size_t OFF_BDLO0 = 41877504;
static const size_t OFF_BHI1  = 42100000;
static const size_t OFF_BLO1  = 42493216;
static const size_t OFF_BDHI1 = 42886432;
static const size_t OFF_BDLO1 = 43017504;   // ends 43,148,576
static const size_t OFF_ENC   = 81920000;
static const size_t OFF_BIN   = 86080000;
static const size_t OFF_ORD   = 86240000;
static const size_t OFF_NRM   = 86400000;
static const size_t OFF_EVAL  = 86560000;
static const size_t OFF_EDST  = 89120000;
static const size_t OFF_KEYS  = 91680000;
static const size_t OFF_AXHI  = 91680000;
static const size_t OFF_AXLO  = 112160000;
static const size_t OFF_NA    = 132640000;  // aliases fhet head
static const size_t OFF_FHET  = 132640000;
static const size_t OFF_GATE  = 173600000;

typedef __attribute__((ext_vector_type(8))) short short8;
typedef __attribute__((ext_vector_type(4))) float f32x4;

__device__ __forceinline__ float selu_f(float x) {
  const float scale = 1.0507009873554805f, alpha = 1.6732632423543772f;
  return x > 0.f ? scale * x : scale * alpha * expm1f(x);
}

__device__ __forceinline__ void split_bf16(float v, __hip_bfloat16& h, __hip_bfloat16& l) {
  h = __float2bfloat16(v);
  l = __float2bfloat16(v - __bfloat162float(h));
}

// ---------------- 1) enc + emb + na_u, 16 points/block ----------------
#define EPB 16
__global__ __launch_bounds__(256) void k_enc_emb(
    const float* __restrict__ X, const float* __restrict__ Wemb,
    const float* __restrict__ bemb, float* __restrict__ enc,
    double* __restrict__ emb, double* __restrict__ na_u) {
  __shared__ float xb[EPB * 15];
  __shared__ double partd[EPB][4];
  const int tid = threadIdx.x;
  const int lane = tid & 63, wid = tid >> 6;
  const int r0 = blockIdx.x * EPB;
  if (tid < EPB * 15) xb[tid] = X[(size_t)r0 * 15 + tid];
  double wcol[DIN];
  #pragma unroll
  for (int c = 0; c < DIN; c++) wcol[c] = (double)Wemb[c * DH + tid];
  const double bcol = (double)bemb[tid];
  __syncthreads();
  #pragma unroll 1
  for (int p = 0; p < EPB; p++) {
    const int id = (int)xb[p * 15];
    double acc = 0.0;
    #pragma unroll
    for (int c = 0; c < 12; c++)
      acc += ((c == id) ? 1.0 : 0.0) * wcol[c];
    #pragma unroll
    for (int c = 12; c < DIN; c++)
      acc += (double)xb[p * 15 + (c - 11)] * wcol[c];
    const double v = acc + bcol;
    emb[(size_t)(r0 + p) * DH + tid] = v;
    double sq = v * v;
    #pragma unroll
    for (int off = 32; off >= 1; off >>= 1) sq += __shfl_xor(sq, off);
    if (lane == 0) partd[p][wid] = sq;
  }
  __syncthreads();
  if (tid < EPB)
    na_u[r0 + tid] = partd[tid][0] + partd[tid][1] + partd[tid][2] + partd[tid][3];
  #pragma unroll
  for (int t = 0; t < 2; t++) {
    int idx = t * 256 + tid;
    if (idx < EPB * DIN) {
      int p = idx / DIN, c = idx - p * DIN;
      int id = (int)xb[p * 15];
      float v = (c < 12) ? ((c == id) ? 1.f : 0.f) : xb[p * 15 + (c - 11)];
      enc[(size_t)(r0 + p) * DIN + c] = v;
    }
  }
}

// ---------------- 2) mul = emb @ rot[:, :25]; bin = argmax([mul,-mul]) (f64) ----------------
#define MULPTS 16
__global__ __launch_bounds__(512) void k_mul(
    const double* __restrict__ emb, const float* __restrict__ rot,
    int* __restrict__ bin_idx) {
  __shared__ double ebuf[MULPTS][258];
  __shared__ float  rotT[25][257];
  __shared__ double mulb[MULPTS][26];
  const int tid = threadIdx.x;
  const int r0 = blockIdx.x * MULPTS;
  for (int idx = tid; idx < 25 * DH; idx += 512) {
    int d = idx / 25, j = idx - d * 25;
    rotT[j][d] = rot[d * 100 + j];
  }
  for (int idx = tid; idx < MULPTS * DH; idx += 512) {
    int p = idx >> 8, d = idx & 255;
    ebuf[p][d] = emb[(size_t)(r0 + p) * DH + d];
  }
  __syncthreads();
  if (tid < MULPTS * 25) {
    int p = tid / 25, j = tid - p * 25;
    double a = 0.0;
    #pragma unroll 4
    for (int d = 0; d < DH; d++) a += ebuf[p][d] * (double)rotT[j][d];
    mulb[p][j] = a;
  }
  __syncthreads();
  if (tid < MULPTS) {
    double best = -1e300; int bi = 0;
    #pragma unroll 1
    for (int jj = 0; jj < 2 * 25; jj++) {
      double v = (jj < 25) ? mulb[tid][jj] : -mulb[tid][jj - 25];
      if (v > best) { best = v; bi = jj; }   // strict > => first occurrence
    }
    bin_idx[r0 + tid] = bi;
  }
}

// ---------------- 3) stable counting sort, parallel ----------------
#define SCH 20
__global__ __launch_bounds__(256) void k_sort(
    const int* __restrict__ bin_idx, int* __restrict__ order) {
  const int b = blockIdx.x;
  __shared__ unsigned short cnt[256][NBINS + 2];
  __shared__ int base[NBINS];
  __shared__ int bl[NLOC];
  const int tid = threadIdx.x;
  for (int j = 0; j < NBINS; j++) cnt[tid][j] = 0;
  for (int n = tid; n < NLOC; n += 256) bl[n] = bin_idx[b * NLOC + n];
  __syncthreads();
  const int s = tid * SCH;
  const int e = (s + SCH < NLOC) ? s + SCH : NLOC;
  for (int n = s; n < e; n++) cnt[tid][bl[n]]++;
  __syncthreads();
  if (tid < NBINS) {
    int run = 0;
    for (int t = 0; t < 256; t++) {
      int c = cnt[t][tid];
      cnt[t][tid] = (unsigned short)run;
      run += c;
    }
    base[tid] = run;
  }
  __syncthreads();
  if (tid == 0) {
    int r = 0;
    for (int j = 0; j < NBINS; j++) { int t = base[j]; base[j] = r; r += t; }
  }
  __syncthreads();
  for (int n = s; n < e; n++) {
    int j = bl[n];
    int pos = base[j] + cnt[tid][j];
    cnt[tid][j]++;
    order[b * NLOC + pos] = n;
  }
}

// ---------------- 4a) pairwise key matrix (f64), 25-row strips (grid 400x4) ----------------
// 4 row-quarters per bin double the resident-wave count vs 2 halves (latency/
// tail-bound kernel). Per-output accumulation sequence (kc 0..7, kk asc,
// .x then .y) unchanged -> keys bit-identical.
#define DQR 112
__global__ __launch_bounds__(256) void k_dist(
    const double* __restrict__ emb, const int* __restrict__ order,
    const double* __restrict__ na_u, double* __restrict__ keys) {
  __shared__ double P[DQR][34];
  __shared__ double naL[DQR];
  __shared__ int rid[DQR];
  const int bin = blockIdx.x;
  const int rq  = blockIdx.y;          // row quarter 0..3 (25 rows each)
  const int gb0 = bin * BSZ;
  const int brow = (bin / NBINS) * NLOC;
  const int tid = threadIdx.x;
  const int tx = tid & 15, ty = tid >> 4;
  if (tid < DQR) {
    int rr = tid < BSZ ? tid : BSZ - 1;
    int g = brow + order[gb0 + rr];
    rid[tid] = g;
    naL[tid] = na_u[g];
  }
  __syncthreads();
  size_t srow[7];
  int scol[7], sr[7];
  #pragma unroll
  for (int q = 0; q < 7; q++) {
    int idx = q * 256 + tid;
    sr[q] = idx >> 4;
    scol[q] = (idx & 15) * 2;
    srow[q] = (size_t)rid[sr[q]] * DH;
  }
  int ar[2];
  #pragma unroll
  for (int i = 0; i < 2; i++) {
    int pr = rq * 25 + ty + 16 * i;
    ar[i] = pr < DQR ? pr : DQR - 1;
  }
  double acc[2][7] = {};
  double2 buf[7];
  #pragma unroll
  for (int q = 0; q < 7; q++)
    buf[q] = *(const double2*)&emb[srow[q] + scol[q]];
  for (int kc = 0; kc < 8; kc++) {
    __syncthreads();
    #pragma unroll
    for (int q = 0; q < 7; q++) {
      P[sr[q]][scol[q]]     = buf[q].x;
      P[sr[q]][scol[q] + 1] = buf[q].y;
    }
    __syncthreads();
    if (kc < 7) {
      #pragma unroll
      for (int q = 0; q < 7; q++)
        buf[q] = *(const double2*)&emb[srow[q] + (kc + 1) * 32 + scol[q]];
    }
    #pragma unroll 1
    for (int kk = 0; kk < 32; kk += 2) {
      double2 b2[7], a2[2];
      #pragma unroll
      for (int j = 0; j < 7; j++) b2[j] = *(const double2*)&P[tx + 16 * j][kk];
      #pragma unroll
      for (int i = 0; i < 2; i++) a2[i] = *(const double2*)&P[ar[i]][kk];
      #pragma unroll
      for (int i = 0; i < 2; i++)
        #pragma unroll
        for (int j = 0; j < 7; j++) acc[i][j] += a2[i].x * b2[j].x;
      #pragma unroll
      for (int i = 0; i < 2; i++)
        #pragma unroll
        for (int j = 0; j < 7; j++) acc[i][j] += a2[i].y * b2[j].y;
    }
  }
  #pragma unroll
  for (int i = 0; i < 2; i++) {
    int lr = ty + 16 * i;
    if (lr >= 25) continue;
    int gi = rq * 25 + lr;
    #pragma unroll
    for (int j = 0; j < 7; j++) {
      int gj = tx + 16 * j;
      if (gj >= BSZ) continue;
      double t = naL[gi] - 2.0 * acc[i][j];   // reference op order
      t += naL[gj];
      keys[(size_t)(gb0 + gi) * KP + gj] = (t > 1e-6) ? t : 1e-6;
    }
  }
}

// ---------------- 4b) top-16 per row: 16 lanes/row, u64 bit-compare ----------------
__global__ __launch_bounds__(256) void k_topk(
    const double* __restrict__ keys, float* __restrict__ evals,
    int* __restrict__ edstl, float* __restrict__ normv) {
  const int g = threadIdx.x >> 4;         // row-group within block (16 rows/block)
  const int l = threadIdx.x & 15;         // lane within row
  const int row = blockIdx.x * 16 + g;
  const unsigned long long* kr =
      (const unsigned long long*)(keys + (size_t)row * KP);
  unsigned long long c[7];
  #pragma unroll
  for (int s = 0; s < 7; s++) {
    int j = s * 16 + l;
    c[s] = (j < BSZ) ? kr[j] : ~0ull;
  }
  float deg = 0.f, myev = 0.f;
  int myidx = 0;
  #pragma unroll 1
  for (int k = 0; k < KNN; k++) {
    unsigned long long mv = c[0];
    int ms = 0;
    #pragma unroll
    for (int s = 1; s < 7; s++)
      if (c[s] < mv) { mv = c[s]; ms = s; }   // strict <: lower slot wins ties
    int idx = ms * 16 + l;
    #pragma unroll
    for (int off = 8; off >= 1; off >>= 1) {
      unsigned long long ov = __shfl_xor(mv, off);
      int oi = __shfl_xor(idx, off);
      if (ov < mv || (ov == mv && oi < idx)) { mv = ov; idx = oi; }
    }
    float ev = expf(-0.1f * sqrtf((float)__longlong_as_double(mv)));
    deg += ev;
    if (l == k) { myev = ev; myidx = idx; }
    const int own = idx & 15, slot = idx >> 4;
    if (l == own) {
      #pragma unroll
      for (int s = 0; s < 7; s++)
        if (slot == s) c[s] = ~0ull;
    }
  }
  evals[(size_t)row * KNN + l] = myev;
  edstl[(size_t)row * KNN + l] = myidx;
  if (l == 0) normv[row] = 1.f / sqrtf(deg + 1e-6f);
}

// ---------------- 5) xenc = selu(enc @ Wenc + benc) -> hi/lo bf16 (16 pts/block) ----------------
#define XPB 16
__global__ __launch_bounds__(256) void k_encmm(
    const float* __restrict__ enc, const float* __restrict__ W,
    const float* __restrict__ bias, __hip_bfloat16* __restrict__ hi,
    __hip_bfloat16* __restrict__ lo) {
  __shared__ float eb[XPB * DIN];
  const int tid = threadIdx.x;
  const int r0 = blockIdx.x * XPB;
  for (int idx = tid; idx < XPB * DIN; idx += 256)
    eb[idx] = enc[(size_t)r0 * DIN + idx];
  float wcol[DIN];
  #pragma unroll
  for (int c = 0; c < DIN; c++) wcol[c] = W[c * DH + tid];
  const float bcol = bias[tid];
  __syncthreads();
  #pragma unroll 1
  for (int p = 0; p < XPB; p++) {
    float acc = 0.f;
    #pragma unroll
    for (int c = 0; c < DIN; c++) acc += eb[p * DIN + c] * wcol[c];
    float v = selu_f(acc + bcol);
    __hip_bfloat16 h, l;
    split_bf16(v, h, l);
    hi[(size_t)(r0 + p) * DH + tid] = h;
    lo[(size_t)(r0 + p) * DH + tid] = l;
  }
}

// ---------------- 6) 8x weight transpose + hi/lo split (one launch, both branches) ----------------
__global__ __launch_bounds__(256) void k_cvt_w8(
    const float* __restrict__ W0, const float* __restrict__ W1,
    const float* __restrict__ W2, const float* __restrict__ W3,
    const float* __restrict__ W4, const float* __restrict__ W5,
    const float* __restrict__ W6, const float* __restrict__ W7,
    __hip_bfloat16* __restrict__ Bhi0, __hip_bfloat16* __restrict__ Blo0,
    __hip_bfloat16* __restrict__ Bdhi0, __hip_bfloat16* __restrict__ Bdlo0,
    __hip_bfloat16* __restrict__ Bhi1, __hip_bfloat16* __restrict__ Blo1,
    __hip_bfloat16* __restrict__ Bdhi1, __hip_bfloat16* __restrict__ Bdlo1) {
  __shared__ float t[32][33];
  const int z = blockIdx.z;
  const float* W = (z == 0) ? W0 : (z == 1) ? W1 : (z == 2) ? W2 : (z == 3) ? W3
                 : (z == 4) ? W4 : (z == 5) ? W5 : (z == 6) ? W6 : W7;
  const int zz = z & 3, br = z >> 2;
  __hip_bfloat16* hi = (zz < 3) ? (br ? Bhi1 : Bhi0) + (size_t)zz * 65536
                                : (br ? Bdhi1 : Bdhi0);
  __hip_bfloat16* lo = (zz < 3) ? (br ? Blo1 : Blo0) + (size_t)zz * 65536
                                : (br ? Bdlo1 : Bdlo0);
  const int tid = threadIdx.x, tx = tid & 31, ty = tid >> 5;
  const int k0 = blockIdx.x * 32, n0 = blockIdx.y * 32;
  #pragma unroll
  for (int r = 0; r < 4; r++)
    t[ty + r * 8][tx] = W[(size_t)(k0 + ty + r * 8) * 256 + n0 + tx];
  __syncthreads();
  #pragma unroll
  for (int r = 0; r < 4; r++) {
    int n = ty + r * 8;
    float v = t[tx][n];
    __hip_bfloat16 h, l;
    split_bf16(v, h, l);
    hi[(size_t)(n0 + n) * 256 + k0 + tx] = h;
    lo[(size_t)(n0 + n) * 256 + k0 + tx] = l;
  }
}

// ---------------- 7) MFMA GEMM, BK=32, XCD-swizzled 1-D grid, inline staging ----------------
#define MF_SMEM (4 * 128 * 40 * 2)
template <int MODE>
__global__ __launch_bounds__(256, 4) void k_mfma(
    const ushort* __restrict__ Ahi, const ushort* __restrict__ Alo,
    const ushort* __restrict__ Bhi, const ushort* __restrict__ Blo,
    const float* __restrict__ bias,
    float* __restrict__ O0, float* __restrict__ O1, float* __restrict__ O2) {
  extern __shared__ char mfs[];
  short* As0 = (short*)mfs;            // Ahi [128][40]
  short* As1 = As0 + 128 * 40;         // Alo
  short* Bs0 = As1 + 128 * 40;         // Bhi
  short* Bs1 = Bs0 + 128 * 40;         // Blo
  const int NX = (MODE == 0) ? 6 : 2;
  const int total = NX * 313;
  const int q = total >> 3, rr8 = total & 7;
  const int xcd = blockIdx.x & 7, pos = blockIdx.x >> 3;
  const int lw = (xcd < rr8 ? xcd * (q + 1) : rr8 * (q + 1) + (xcd - rr8) * q) + pos;
  const int m0 = (lw / NX) * 128;
  const int nx = lw - (lw / NX) * NX;
  const int n0 = nx * 128;
  const int tid = threadIdx.x;
  const int lane = tid & 63, wid = tid >> 6;
  const int wr = wid >> 1, wc = wid & 1;
  const int lm = lane & 15, lg = lane >> 4;
  f32x4 acc[4][4];
  #pragma unroll
  for (int i = 0; i < 4; i++)
    #pragma unroll
    for (int j = 0; j < 4; j++)
      #pragma unroll
      for (int r = 0; r < 4; r++) acc[i][j][r] = 0.f;

  for (int k0 = 0; k0 < 256; k0 += 32) {
    #pragma unroll
    for (int it = 0; it < 2; it++) {
      int idx = it * 256 + tid;
      int r = idx >> 2, c = (idx & 3) * 8;
      int gm = m0 + r; if (gm >= NPTS) gm = NPTS - 1;
      *(uint4*)&As0[r * 40 + c] = *(const uint4*)&Ahi[(size_t)gm * 256 + k0 + c];
      *(uint4*)&As1[r * 40 + c] = *(const uint4*)&Alo[(size_t)gm * 256 + k0 + c];
      *(uint4*)&Bs0[r * 40 + c] = *(const uint4*)&Bhi[(size_t)(n0 + r) * 256 + k0 + c];
      *(uint4*)&Bs1[r * 40 + c] = *(const uint4*)&Blo[(size_t)(n0 + r) * 256 + k0 + c];
    }
    __syncthreads();
    const int lk = lg * 8;
    short8 aH[4], bH[4], aL[4], bL[4];
    #pragma unroll
    for (int mf = 0; mf < 4; mf++)
      aH[mf] = *(const short8*)&As0[(wr * 64 + mf * 16 + lm) * 40 + lk];
    #pragma unroll
    for (int nf = 0; nf < 4; nf++)
      bH[nf] = *(const short8*)&Bs0[(wc * 64 + nf * 16 + lm) * 40 + lk];
    #pragma unroll
    for (int mf = 0; mf < 4; mf++)
      #pragma unroll
      for (int nf = 0; nf < 4; nf++)
        acc[mf][nf] = __builtin_amdgcn_mfma_f32_16x16x32_bf16(aH[mf], bH[nf], acc[mf][nf], 0, 0, 0);
    #pragma unroll
    for (int nf = 0; nf < 4; nf++)
      bL[nf] = *(const short8*)&Bs1[(wc * 64 + nf * 16 + lm) * 40 + lk];
    #pragma unroll
    for (int mf = 0; mf < 4; mf++)
      #pragma unroll
      for (int nf = 0; nf < 4; nf++)
        acc[mf][nf] = __builtin_amdgcn_mfma_f32_16x16x32_bf16(aH[mf], bL[nf], acc[mf][nf], 0, 0, 0);
    #pragma unroll
    for (int mf = 0; mf < 4; mf++)
      aL[mf] = *(const short8*)&As1[(wr * 64 + mf * 16 + lm) * 40 + lk];
    #pragma unroll
    for (int mf = 0; mf < 4; mf++)
      #pragma unroll
      for (int nf = 0; nf < 4; nf++)
        acc[mf][nf] = __builtin_amdgcn_mfma_f32_16x16x32_bf16(aL[mf], bH[nf], acc[mf][nf], 0, 0, 0);
    __syncthreads();
  }

  float* Out; int cb;
  if (MODE == 0) {
    const int seg = nx >> 1;
    Out = (seg == 0) ? O0 : ((seg == 1) ? O1 : O2);
    cb = (nx & 1) * 128;
  } else {
    Out = O0; cb = n0;
  }
  const bool do_gate = (MODE == 0) && (nx >> 1) == 2;
  #pragma unroll
  for (int mf = 0; mf < 4; mf++) {
    const int gm0 = m0 + wr * 64 + mf * 16 + lg * 4;
    #pragma unroll
    for (int nf = 0; nf < 4; nf++) {
      const int gn = cb + wc * 64 + nf * 16 + lm;
      #pragma unroll
      for (int r = 0; r < 4; r++) {
        const int gm = gm0 + r;
        if (gm >= NPTS) continue;
        float c = acc[mf][nf][r];
        if (MODE == 1)      c = selu_f(c + bias[gn]);
        else if (do_gate)   c = 1.f / (1.f + expf(-(c + bias[gn])));
        Out[(size_t)gm * 256 + gn] = c;
      }
    }
  }
}

// ---------------- 8) per-bin gather-combine -> y hi/lo bf16 (1024 threads) ----------------
#define GAT_SMEM (100 * 256 * 4 + 1600 * 8 + 100 * 4 + 100 * 4)
__global__ __launch_bounds__(1024) void k_gatherb(
    const float* __restrict__ hth, const float* __restrict__ fhet,
    const float* __restrict__ gate, const float* __restrict__ evals,
    const int* __restrict__ edstl, const int* __restrict__ order,
    const float* __restrict__ normv, __hip_bfloat16* __restrict__ yhi,
    __hip_bfloat16* __restrict__ ylo) {
  extern __shared__ char gsm[];
  float*  hl  = (float*)gsm;                            // [100][256]
  float2* cwL = (float2*)(gsm + 102400);                // [1600] (wk, loc-bits)
  int*    idsL = (int*)(gsm + 102400 + 12800);          // [100]
  float*  nvL  = (float*)(gsm + 102400 + 12800 + 400);  // [100]
  const int bin = blockIdx.x;
  const int gb0 = bin * 100;
  const int brow = (bin / NBINS) * NLOC;
  const int tid = threadIdx.x;
  const int p = tid >> 8, d = tid & 255;
  if (tid < BSZ) {
    idsL[tid] = order[gb0 + tid];
    nvL[tid] = normv[gb0 + tid];
  }
  __syncthreads();
  for (int t = tid; t < BSZ * KNN; t += 1024) {
    int lj = edstl[(size_t)gb0 * KNN + t];
    cwL[t] = make_float2(evals[(size_t)gb0 * KNN + t] * nvL[lj],
                         __int_as_float(lj));
  }
  for (int idx = tid; idx < BSZ * DH; idx += 1024) {
    int i = idx >> 8, dd = idx & 255;
    hl[i * 256 + dd] = hth[(size_t)(brow + idsL[i]) * DH + dd];
  }
  __syncthreads();
  size_t srow_n = (size_t)(brow + idsL[p]) * DH;
  float g_n = gate[srow_n + d], fh_n = fhet[srow_n + d];
  #pragma unroll 1
  for (int ii = 0; ii < 25; ii++) {
    const int i = ii * 4 + p;
    const size_t srow = srow_n;
    const float g = g_n, fh = fh_n;
    if (ii < 24) {
      srow_n = (size_t)(brow + idsL[i + 4]) * DH;
      g_n = gate[srow_n + d];
      fh_n = fhet[srow_n + d];
    }
    float acc = 0.f;
    #pragma unroll
    for (int k = 0; k < KNN; k++) {
      float2 cw = cwL[i * KNN + k];
      acc += cw.x * hl[__float_as_int(cw.y) * 256 + d];
    }
    float v = selu_f(g * (nvL[i] * acc) + (1.f - g) * fh);
    __hip_bfloat16 h, l;
    split_bf16(v, h, l);
    yhi[srow + d] = h;
    ylo[srow + d] = l;
  }
}

// ---------------- 9) out = z @ Wout + bout ----------------
template <int OW>
__global__ __launch_bounds__(256) void k_out(
    const float* __restrict__ Z, const float* __restrict__ W,
    const float* __restrict__ bias, float* __restrict__ out) {
  const int p0 = blockIdx.x * 32;
  __shared__ float zb[32][257];
  const int tid = threadIdx.x;
  for (int idx = tid; idx < 32 * DH; idx += 256) {
    int p = idx >> 8, d = idx & 255;
    zb[p][d] = Z[(size_t)(p0 + p) * DH + d];
  }
  __syncthreads();
  if (tid < 32 * OW) {
    int p = tid / OW, o = tid - (tid / OW) * OW;
    float acc = 0.f;
    #pragma unroll 4
    for (int d = 0; d < DH; d++) acc += zb[p][d] * W[d * OW + o];
    out[(size_t)(p0 + p) * OW + o] = acc + bias[o];
  }
}

// ---------------- host ----------------
extern "C" void kernel_launch(void* const* d_in, const int* in_sizes, int n_in,
                              void* d_out, int out_size, void* d_ws, size_t ws_size,
                              hipStream_t stream) {
  const float* X     = (const float*)d_in[0];
  const float* rot   = (const float*)d_in[1];
  const float* W_emb = (const float*)d_in[2];
  const float* b_emb = (const float*)d_in[3];
  const float* Wenc[2]  = {(const float*)d_in[4],  (const float*)d_in[14]};
  const float* benc[2]  = {(const float*)d_in[5],  (const float*)d_in[15]};
  const float* theta[2] = {(const float*)d_in[6],  (const float*)d_in[16]};
  const float* Wh[2]    = {(const float*)d_in[7],  (const float*)d_in[17]};
  const float* Wt[2]    = {(const float*)d_in[8],  (const float*)d_in[18]};
  const float* bt[2]    = {(const float*)d_in[9],  (const float*)d_in[19]};
  const float* Wdec[2]  = {(const float*)d_in[10], (const float*)d_in[20]};
  const float* bdec[2]  = {(const float*)d_in[11], (const float*)d_in[21]};
  const float* Wout[2]  = {(const float*)d_in[12], (const float*)d_in[22]};
  const float* bout[2]  = {(const float*)d_in[13], (const float*)d_in[23]};

  char* w = (char*)d_ws;
  double* emb   = (double*)(w + 0);
  float*  hth   = (float*)(w + 0);                  // alias emb (dead after k_dist)
  __hip_bfloat16* Bhi[2]  = {(__hip_bfloat16*)(w + OFF_BHI0),  (__hip_bfloat16*)(w + OFF_BHI1)};
  __hip_bfloat16* Blo[2]  = {(__hip_bfloat16*)(w + OFF_BLO0),  (__hip_bfloat16*)(w + OFF_BLO1)};
  __hip_bfloat16* Bdhi[2] = {(__hip_bfloat16*)(w + OFF_BDHI0), (__hip_bfloat16*)(w + OFF_BDHI1)};
  __hip_bfloat16* Bdlo[2] = {(__hip_bfloat16*)(w + OFF_BDLO0), (__hip_bfloat16*)(w + OFF_BDLO1)};
  float*  enc   = (float*)(w + OFF_ENC);
  int*    binid = (int*)(w + OFF_BIN);
  int*    order = (int*)(w + OFF_ORD);
  float*  normv = (float*)(w + OFF_NRM);            // sorted-position indexed
  float*  evals = (float*)(w + OFF_EVAL);
  int*    edstl = (int*)(w + OFF_EDST);             // local in-bin dst indices
  double* keys  = (double*)(w + OFF_KEYS);          // dead after k_topk
  double* na_u  = (double*)(w + OFF_NA);            // aliases fhet head
  __hip_bfloat16* Axhi = (__hip_bfloat16*)(w + OFF_AXHI);  // also yhi
  __hip_bfloat16* Axlo = (__hip_bfloat16*)(w + OFF_AXLO);  // also ylo
  float*  fhet  = (float*)(w + OFF_FHET);
  float*  gate  = (float*)(w + OFF_GATE);
  float*  zbuf  = (float*)(w + OFF_GATE);           // alias gate (dead after gather)
  float*  outp  = (float*)d_out;

  (void)hipFuncSetAttribute(reinterpret_cast<const void*>(k_gatherb),
                            hipFuncAttributeMaxDynamicSharedMemorySize, GAT_SMEM);
  (void)hipFuncSetAttribute(reinterpret_cast<const void*>(k_mfma<0>),
                            hipFuncAttributeMaxDynamicSharedMemorySize, MF_SMEM);
  (void)hipFuncSetAttribute(reinterpret_cast<const void*>(k_mfma<1>),
                            hipFuncAttributeMaxDynamicSharedMemorySize, MF_SMEM);

  k_enc_emb<<<NPTS / EPB, 256, 0, stream>>>(X, W_emb, b_emb, enc, emb, na_u);
  k_mul<<<NPTS / MULPTS, 512, 0, stream>>>(emb, rot, binid);
  k_sort<<<NB, 256, 0, stream>>>(binid, order);
  k_dist<<<dim3(NB * NBINS, 4), 256, 0, stream>>>(emb, order, na_u, keys);
  k_topk<<<NPTS / 16, 256, 0, stream>>>(keys, evals, edstl, normv);
  k_cvt_w8<<<dim3(8, 8, 8), 256, 0, stream>>>(
      theta[0], Wh[0], Wt[0], Wdec[0], theta[1], Wh[1], Wt[1], Wdec[1],
      Bhi[0], Blo[0], Bdhi[0], Bdlo[0], Bhi[1], Blo[1], Bdhi[1], Bdlo[1]);

  for (int br = 0; br < 2; br++) {
    k_encmm<<<NPTS / XPB, 256, 0, stream>>>(enc, Wenc[br], benc[br], Axhi, Axlo);
    k_mfma<0><<<6 * 313, 256, MF_SMEM, stream>>>((const ushort*)Axhi, (const ushort*)Axlo,
                                                 (const ushort*)Bhi[br], (const ushort*)Blo[br],
                                                 bt[br], hth, fhet, gate);
    k_gatherb<<<NB * NBINS, 1024, GAT_SMEM, stream>>>(hth, fhet, gate, evals, edstl,
                                                      order, normv, Axhi, Axlo);
    k_mfma<1><<<2 * 313, 256, MF_SMEM, stream>>>((const ushort*)Axhi, (const ushort*)Axlo,
                                                 (const ushort*)Bdhi[br], (const ushort*)Bdlo[br],
                                                 bdec[br], zbuf, nullptr, nullptr);
    if (br == 0) k_out<8><<<NPTS / 32, 256, 0, stream>>>(zbuf, Wout[0], bout[0], outp);
    else         k_out<4><<<NPTS / 32, 256, 0, stream>>>(zbuf, Wout[1], bout[1], outp + (size_t)NPTS * 8);
  }
}

// Round 19
// 657.965 us; speedup vs baseline: 1.0370x; 1.0370x over previous
//
#include <hip/hip_runtime.h>
#include <hip/hip_bf16.h>
#include <cstdint>
#include <cstddef>

// ---------------- problem constants ----------------
#define NB     8
#define NLOC   5000
#define NPTS   40000      // NB*NLOC
#define DIN    26
#define DH     256
#define NBINS  50
#define BSZ    100
#define KNN    16
#define KP     104        // keys row pitch (f64)

// ---------------- workspace layout (bytes), total 214,560,000 ----------------
static const size_t OFF_BHI0  = 40960000;
static const size_t OFF_BLO0  = 41353216;
static const size_t OFF_BDHI0 = 41746432;
static const size_t OFF_BDLO0 = 41877504;
static const size_t OFF_BHI1  = 42100000;
static const size_t OFF_BLO1  = 42493216;
static const size_t OFF_BDHI1 = 42886432;
static const size_t OFF_BDLO1 = 43017504;   // ends 43,148,576
static const size_t OFF_ENC   = 81920000;
static const size_t OFF_BIN   = 86080000;
static const size_t OFF_ORD   = 86240000;
static const size_t OFF_NRM   = 86400000;
static const size_t OFF_EVAL  = 86560000;
static const size_t OFF_EDST  = 89120000;
static const size_t OFF_KEYS  = 91680000;
static const size_t OFF_AXHI  = 91680000;
static const size_t OFF_AXLO  = 112160000;
static const size_t OFF_NA    = 132640000;  // aliases fhet head
static const size_t OFF_FHET  = 132640000;
static const size_t OFF_GATE  = 173600000;

typedef __attribute__((ext_vector_type(8))) short short8;
typedef __attribute__((ext_vector_type(4))) float f32x4;

__device__ __forceinline__ float selu_f(float x) {
  const float scale = 1.0507009873554805f, alpha = 1.6732632423543772f;
  return x > 0.f ? scale * x : scale * alpha * expm1f(x);
}

__device__ __forceinline__ void split_bf16(float v, __hip_bfloat16& h, __hip_bfloat16& l) {
  h = __float2bfloat16(v);
  l = __float2bfloat16(v - __bfloat162float(h));
}

// ---------------- 1) enc + emb + na_u, 16 points/block ----------------
#define EPB 16
__global__ __launch_bounds__(256) void k_enc_emb(
    const float* __restrict__ X, const float* __restrict__ Wemb,
    const float* __restrict__ bemb, float* __restrict__ enc,
    double* __restrict__ emb, double* __restrict__ na_u) {
  __shared__ float xb[EPB * 15];
  __shared__ double partd[EPB][4];
  const int tid = threadIdx.x;
  const int lane = tid & 63, wid = tid >> 6;
  const int r0 = blockIdx.x * EPB;
  if (tid < EPB * 15) xb[tid] = X[(size_t)r0 * 15 + tid];
  double wcol[DIN];
  #pragma unroll
  for (int c = 0; c < DIN; c++) wcol[c] = (double)Wemb[c * DH + tid];
  const double bcol = (double)bemb[tid];
  __syncthreads();
  #pragma unroll 1
  for (int p = 0; p < EPB; p++) {
    const int id = (int)xb[p * 15];
    double acc = 0.0;
    #pragma unroll
    for (int c = 0; c < 12; c++)
      acc += ((c == id) ? 1.0 : 0.0) * wcol[c];
    #pragma unroll
    for (int c = 12; c < DIN; c++)
      acc += (double)xb[p * 15 + (c - 11)] * wcol[c];
    const double v = acc + bcol;
    emb[(size_t)(r0 + p) * DH + tid] = v;
    double sq = v * v;
    #pragma unroll
    for (int off = 32; off >= 1; off >>= 1) sq += __shfl_xor(sq, off);
    if (lane == 0) partd[p][wid] = sq;
  }
  __syncthreads();
  if (tid < EPB)
    na_u[r0 + tid] = partd[tid][0] + partd[tid][1] + partd[tid][2] + partd[tid][3];
  #pragma unroll
  for (int t = 0; t < 2; t++) {
    int idx = t * 256 + tid;
    if (idx < EPB * DIN) {
      int p = idx / DIN, c = idx - p * DIN;
      int id = (int)xb[p * 15];
      float v = (c < 12) ? ((c == id) ? 1.f : 0.f) : xb[p * 15 + (c - 11)];
      enc[(size_t)(r0 + p) * DIN + c] = v;
    }
  }
}

// ---------------- 2) mul = emb @ rot[:, :25]; bin = argmax([mul,-mul]) (f64) ----------------
#define MULPTS 16
__global__ __launch_bounds__(512) void k_mul(
    const double* __restrict__ emb, const float* __restrict__ rot,
    int* __restrict__ bin_idx) {
  __shared__ double ebuf[MULPTS][258];
  __shared__ float  rotT[25][257];
  __shared__ double mulb[MULPTS][26];
  const int tid = threadIdx.x;
  const int r0 = blockIdx.x * MULPTS;
  for (int idx = tid; idx < 25 * DH; idx += 512) {
    int d = idx / 25, j = idx - d * 25;
    rotT[j][d] = rot[d * 100 + j];
  }
  for (int idx = tid; idx < MULPTS * DH; idx += 512) {
    int p = idx >> 8, d = idx & 255;
    ebuf[p][d] = emb[(size_t)(r0 + p) * DH + d];
  }
  __syncthreads();
  if (tid < MULPTS * 25) {
    int p = tid / 25, j = tid - p * 25;
    double a = 0.0;
    #pragma unroll 4
    for (int d = 0; d < DH; d++) a += ebuf[p][d] * (double)rotT[j][d];
    mulb[p][j] = a;
  }
  __syncthreads();
  if (tid < MULPTS) {
    double best = -1e300; int bi = 0;
    #pragma unroll 1
    for (int jj = 0; jj < 2 * 25; jj++) {
      double v = (jj < 25) ? mulb[tid][jj] : -mulb[tid][jj - 25];
      if (v > best) { best = v; bi = jj; }   // strict > => first occurrence
    }
    bin_idx[r0 + tid] = bi;
  }
}

// ---------------- 3) stable counting sort, parallel ----------------
#define SCH 20
__global__ __launch_bounds__(256) void k_sort(
    const int* __restrict__ bin_idx, int* __restrict__ order) {
  const int b = blockIdx.x;
  __shared__ unsigned short cnt[256][NBINS + 2];
  __shared__ int base[NBINS];
  __shared__ int bl[NLOC];
  const int tid = threadIdx.x;
  for (int j = 0; j < NBINS; j++) cnt[tid][j] = 0;
  for (int n = tid; n < NLOC; n += 256) bl[n] = bin_idx[b * NLOC + n];
  __syncthreads();
  const int s = tid * SCH;
  const int e = (s + SCH < NLOC) ? s + SCH : NLOC;
  for (int n = s; n < e; n++) cnt[tid][bl[n]]++;
  __syncthreads();
  if (tid < NBINS) {
    int run = 0;
    for (int t = 0; t < 256; t++) {
      int c = cnt[t][tid];
      cnt[t][tid] = (unsigned short)run;
      run += c;
    }
    base[tid] = run;
  }
  __syncthreads();
  if (tid == 0) {
    int r = 0;
    for (int j = 0; j < NBINS; j++) { int t = base[j]; base[j] = r; r += t; }
  }
  __syncthreads();
  for (int n = s; n < e; n++) {
    int j = bl[n];
    int pos = base[j] + cnt[tid][j];
    cnt[tid][j]++;
    order[b * NLOC + pos] = n;
  }
}

// ---------------- 4a) pairwise key matrix (f64), FULL 112x112 tile, 1 block/bin ----------------
// acc[7][7]/thread: 14 ds_read_b128 per kk-pair for 98 FMAs (7 FMA/read vs
// 5.1 in the 2-half version) -> LDS-issue-bound time drops ~35%. Grid 400,
// ~2 blocks/CU co-resident, no tail. Per-output accumulation order (kc 0..7,
// kk-pair asc, .x then .y) unchanged -> keys bit-identical.
#define DQR 112
__global__ __launch_bounds__(256) void k_dist(
    const double* __restrict__ emb, const int* __restrict__ order,
    const double* __restrict__ na_u, double* __restrict__ keys) {
  __shared__ double P[DQR][34];
  __shared__ double naL[DQR];
  __shared__ int rid[DQR];
  const int bin = blockIdx.x;
  const int gb0 = bin * BSZ;
  const int brow = (bin / NBINS) * NLOC;
  const int tid = threadIdx.x;
  const int tx = tid & 15, ty = tid >> 4;
  if (tid < DQR) {
    int rr = tid < BSZ ? tid : BSZ - 1;
    int g = brow + order[gb0 + rr];
    rid[tid] = g;
    naL[tid] = na_u[g];
  }
  __syncthreads();
  size_t srow[7];
  int scol[7], sr[7];
  #pragma unroll
  for (int q = 0; q < 7; q++) {
    int idx = q * 256 + tid;
    sr[q] = idx >> 4;
    scol[q] = (idx & 15) * 2;
    srow[q] = (size_t)rid[sr[q]] * DH;
  }
  double acc[7][7] = {};
  double2 buf[7];
  #pragma unroll
  for (int q = 0; q < 7; q++)
    buf[q] = *(const double2*)&emb[srow[q] + scol[q]];
  for (int kc = 0; kc < 8; kc++) {
    __syncthreads();
    #pragma unroll
    for (int q = 0; q < 7; q++) {
      P[sr[q]][scol[q]]     = buf[q].x;
      P[sr[q]][scol[q] + 1] = buf[q].y;
    }
    __syncthreads();
    if (kc < 7) {
      #pragma unroll
      for (int q = 0; q < 7; q++)
        buf[q] = *(const double2*)&emb[srow[q] + (kc + 1) * 32 + scol[q]];
    }
    #pragma unroll 1
    for (int kk = 0; kk < 32; kk += 2) {
      double2 b2[7], a2[7];
      #pragma unroll
      for (int j = 0; j < 7; j++) b2[j] = *(const double2*)&P[tx + 16 * j][kk];
      #pragma unroll
      for (int i = 0; i < 7; i++) a2[i] = *(const double2*)&P[ty + 16 * i][kk];
      #pragma unroll
      for (int i = 0; i < 7; i++)
        #pragma unroll
        for (int j = 0; j < 7; j++) acc[i][j] += a2[i].x * b2[j].x;
      #pragma unroll
      for (int i = 0; i < 7; i++)
        #pragma unroll
        for (int j = 0; j < 7; j++) acc[i][j] += a2[i].y * b2[j].y;
    }
  }
  #pragma unroll
  for (int i = 0; i < 7; i++) {
    int gi = ty + 16 * i;
    if (gi >= BSZ) continue;
    #pragma unroll
    for (int j = 0; j < 7; j++) {
      int gj = tx + 16 * j;
      if (gj >= BSZ) continue;
      double t = naL[gi] - 2.0 * acc[i][j];   // reference op order
      t += naL[gj];
      keys[(size_t)(gb0 + gi) * KP + gj] = (t > 1e-6) ? t : 1e-6;
    }
  }
}

// ---------------- 4b) top-16 per row: 16 lanes/row, u64 bit-compare ----------------
__global__ __launch_bounds__(256) void k_topk(
    const double* __restrict__ keys, float* __restrict__ evals,
    int* __restrict__ edstl, float* __restrict__ normv) {
  const int g = threadIdx.x >> 4;         // row-group within block (16 rows/block)
  const int l = threadIdx.x & 15;         // lane within row
  const int row = blockIdx.x * 16 + g;
  const unsigned long long* kr =
      (const unsigned long long*)(keys + (size_t)row * KP);
  unsigned long long c[7];
  #pragma unroll
  for (int s = 0; s < 7; s++) {
    int j = s * 16 + l;
    c[s] = (j < BSZ) ? kr[j] : ~0ull;
  }
  float deg = 0.f, myev = 0.f;
  int myidx = 0;
  #pragma unroll 1
  for (int k = 0; k < KNN; k++) {
    unsigned long long mv = c[0];
    int ms = 0;
    #pragma unroll
    for (int s = 1; s < 7; s++)
      if (c[s] < mv) { mv = c[s]; ms = s; }   // strict <: lower slot wins ties
    int idx = ms * 16 + l;
    #pragma unroll
    for (int off = 8; off >= 1; off >>= 1) {
      unsigned long long ov = __shfl_xor(mv, off);
      int oi = __shfl_xor(idx, off);
      if (ov < mv || (ov == mv && oi < idx)) { mv = ov; idx = oi; }
    }
    float ev = expf(-0.1f * sqrtf((float)__longlong_as_double(mv)));
    deg += ev;
    if (l == k) { myev = ev; myidx = idx; }
    const int own = idx & 15, slot = idx >> 4;
    if (l == own) {
      #pragma unroll
      for (int s = 0; s < 7; s++)
        if (slot == s) c[s] = ~0ull;
    }
  }
  evals[(size_t)row * KNN + l] = myev;
  edstl[(size_t)row * KNN + l] = myidx;
  if (l == 0) normv[row] = 1.f / sqrtf(deg + 1e-6f);
}

// ---------------- 5) xenc = selu(enc @ Wenc + benc) -> hi/lo bf16 (16 pts/block) ----------------
#define XPB 16
__global__ __launch_bounds__(256) void k_encmm(
    const float* __restrict__ enc, const float* __restrict__ W,
    const float* __restrict__ bias, __hip_bfloat16* __restrict__ hi,
    __hip_bfloat16* __restrict__ lo) {
  __shared__ float eb[XPB * DIN];
  const int tid = threadIdx.x;
  const int r0 = blockIdx.x * XPB;
  for (int idx = tid; idx < XPB * DIN; idx += 256)
    eb[idx] = enc[(size_t)r0 * DIN + idx];
  float wcol[DIN];
  #pragma unroll
  for (int c = 0; c < DIN; c++) wcol[c] = W[c * DH + tid];
  const float bcol = bias[tid];
  __syncthreads();
  #pragma unroll 1
  for (int p = 0; p < XPB; p++) {
    float acc = 0.f;
    #pragma unroll
    for (int c = 0; c < DIN; c++) acc += eb[p * DIN + c] * wcol[c];
    float v = selu_f(acc + bcol);
    __hip_bfloat16 h, l;
    split_bf16(v, h, l);
    hi[(size_t)(r0 + p) * DH + tid] = h;
    lo[(size_t)(r0 + p) * DH + tid] = l;
  }
}

// ---------------- 6) 8x weight transpose + hi/lo split (one launch, both branches) ----------------
__global__ __launch_bounds__(256) void k_cvt_w8(
    const float* __restrict__ W0, const float* __restrict__ W1,
    const float* __restrict__ W2, const float* __restrict__ W3,
    const float* __restrict__ W4, const float* __restrict__ W5,
    const float* __restrict__ W6, const float* __restrict__ W7,
    __hip_bfloat16* __restrict__ Bhi0, __hip_bfloat16* __restrict__ Blo0,
    __hip_bfloat16* __restrict__ Bdhi0, __hip_bfloat16* __restrict__ Bdlo0,
    __hip_bfloat16* __restrict__ Bhi1, __hip_bfloat16* __restrict__ Blo1,
    __hip_bfloat16* __restrict__ Bdhi1, __hip_bfloat16* __restrict__ Bdlo1) {
  __shared__ float t[32][33];
  const int z = blockIdx.z;
  const float* W = (z == 0) ? W0 : (z == 1) ? W1 : (z == 2) ? W2 : (z == 3) ? W3
                 : (z == 4) ? W4 : (z == 5) ? W5 : (z == 6) ? W6 : W7;
  const int zz = z & 3, br = z >> 2;
  __hip_bfloat16* hi = (zz < 3) ? (br ? Bhi1 : Bhi0) + (size_t)zz * 65536
                                : (br ? Bdhi1 : Bdhi0);
  __hip_bfloat16* lo = (zz < 3) ? (br ? Blo1 : Blo0) + (size_t)zz * 65536
                                : (br ? Bdlo1 : Bdlo0);
  const int tid = threadIdx.x, tx = tid & 31, ty = tid >> 5;
  const int k0 = blockIdx.x * 32, n0 = blockIdx.y * 32;
  #pragma unroll
  for (int r = 0; r < 4; r++)
    t[ty + r * 8][tx] = W[(size_t)(k0 + ty + r * 8) * 256 + n0 + tx];
  __syncthreads();
  #pragma unroll
  for (int r = 0; r < 4; r++) {
    int n = ty + r * 8;
    float v = t[tx][n];
    __hip_bfloat16 h, l;
    split_bf16(v, h, l);
    hi[(size_t)(n0 + n) * 256 + k0 + tx] = h;
    lo[(size_t)(n0 + n) * 256 + k0 + tx] = l;
  }
}

// ---------------- 7) MFMA GEMM, BK=32, XCD-swizzled 1-D grid, inline staging ----------------
#define MF_SMEM (4 * 128 * 40 * 2)
template <int MODE>
__global__ __launch_bounds__(256, 4) void k_mfma(
    const ushort* __restrict__ Ahi, const ushort* __restrict__ Alo,
    const ushort* __restrict__ Bhi, const ushort* __restrict__ Blo,
    const float* __restrict__ bias,
    float* __restrict__ O0, float* __restrict__ O1, float* __restrict__ O2) {
  extern __shared__ char mfs[];
  short* As0 = (short*)mfs;            // Ahi [128][40]
  short* As1 = As0 + 128 * 40;         // Alo
  short* Bs0 = As1 + 128 * 40;         // Bhi
  short* Bs1 = Bs0 + 128 * 40;         // Blo
  const int NX = (MODE == 0) ? 6 : 2;
  const int total = NX * 313;
  const int q = total >> 3, rr8 = total & 7;
  const int xcd = blockIdx.x & 7, pos = blockIdx.x >> 3;
  const int lw = (xcd < rr8 ? xcd * (q + 1) : rr8 * (q + 1) + (xcd - rr8) * q) + pos;
  const int m0 = (lw / NX) * 128;
  const int nx = lw - (lw / NX) * NX;
  const int n0 = nx * 128;
  const int tid = threadIdx.x;
  const int lane = tid & 63, wid = tid >> 6;
  const int wr = wid >> 1, wc = wid & 1;
  const int lm = lane & 15, lg = lane >> 4;
  f32x4 acc[4][4];
  #pragma unroll
  for (int i = 0; i < 4; i++)
    #pragma unroll
    for (int j = 0; j < 4; j++)
      #pragma unroll
      for (int r = 0; r < 4; r++) acc[i][j][r] = 0.f;

  for (int k0 = 0; k0 < 256; k0 += 32) {
    #pragma unroll
    for (int it = 0; it < 2; it++) {
      int idx = it * 256 + tid;
      int r = idx >> 2, c = (idx & 3) * 8;
      int gm = m0 + r; if (gm >= NPTS) gm = NPTS - 1;
      *(uint4*)&As0[r * 40 + c] = *(const uint4*)&Ahi[(size_t)gm * 256 + k0 + c];
      *(uint4*)&As1[r * 40 + c] = *(const uint4*)&Alo[(size_t)gm * 256 + k0 + c];
      *(uint4*)&Bs0[r * 40 + c] = *(const uint4*)&Bhi[(size_t)(n0 + r) * 256 + k0 + c];
      *(uint4*)&Bs1[r * 40 + c] = *(const uint4*)&Blo[(size_t)(n0 + r) * 256 + k0 + c];
    }
    __syncthreads();
    const int lk = lg * 8;
    short8 aH[4], bH[4], aL[4], bL[4];
    #pragma unroll
    for (int mf = 0; mf < 4; mf++)
      aH[mf] = *(const short8*)&As0[(wr * 64 + mf * 16 + lm) * 40 + lk];
    #pragma unroll
    for (int nf = 0; nf < 4; nf++)
      bH[nf] = *(const short8*)&Bs0[(wc * 64 + nf * 16 + lm) * 40 + lk];
    #pragma unroll
    for (int mf = 0; mf < 4; mf++)
      #pragma unroll
      for (int nf = 0; nf < 4; nf++)
        acc[mf][nf] = __builtin_amdgcn_mfma_f32_16x16x32_bf16(aH[mf], bH[nf], acc[mf][nf], 0, 0, 0);
    #pragma unroll
    for (int nf = 0; nf < 4; nf++)
      bL[nf] = *(const short8*)&Bs1[(wc * 64 + nf * 16 + lm) * 40 + lk];
    #pragma unroll
    for (int mf = 0; mf < 4; mf++)
      #pragma unroll
      for (int nf = 0; nf < 4; nf++)
        acc[mf][nf] = __builtin_amdgcn_mfma_f32_16x16x32_bf16(aH[mf], bL[nf], acc[mf][nf], 0, 0, 0);
    #pragma unroll
    for (int mf = 0; mf < 4; mf++)
      aL[mf] = *(const short8*)&As1[(wr * 64 + mf * 16 + lm) * 40 + lk];
    #pragma unroll
    for (int mf = 0; mf < 4; mf++)
      #pragma unroll
      for (int nf = 0; nf < 4; nf++)
        acc[mf][nf] = __builtin_amdgcn_mfma_f32_16x16x32_bf16(aL[mf], bH[nf], acc[mf][nf], 0, 0, 0);
    __syncthreads();
  }

  float* Out; int cb;
  if (MODE == 0) {
    const int seg = nx >> 1;
    Out = (seg == 0) ? O0 : ((seg == 1) ? O1 : O2);
    cb = (nx & 1) * 128;
  } else {
    Out = O0; cb = n0;
  }
  const bool do_gate = (MODE == 0) && (nx >> 1) == 2;
  #pragma unroll
  for (int mf = 0; mf < 4; mf++) {
    const int gm0 = m0 + wr * 64 + mf * 16 + lg * 4;
    #pragma unroll
    for (int nf = 0; nf < 4; nf++) {
      const int gn = cb + wc * 64 + nf * 16 + lm;
      #pragma unroll
      for (int r = 0; r < 4; r++) {
        const int gm = gm0 + r;
        if (gm >= NPTS) continue;
        float c = acc[mf][nf][r];
        if (MODE == 1)      c = selu_f(c + bias[gn]);
        else if (do_gate)   c = 1.f / (1.f + expf(-(c + bias[gn])));
        Out[(size_t)gm * 256 + gn] = c;
      }
    }
  }
}

// ---------------- 8) per-bin gather-combine -> y hi/lo bf16 (1024 threads) ----------------
#define GAT_SMEM (100 * 256 * 4 + 1600 * 8 + 100 * 4 + 100 * 4)
__global__ __launch_bounds__(1024) void k_gatherb(
    const float* __restrict__ hth, const float* __restrict__ fhet,
    const float* __restrict__ gate, const float* __restrict__ evals,
    const int* __restrict__ edstl, const int* __restrict__ order,
    const float* __restrict__ normv, __hip_bfloat16* __restrict__ yhi,
    __hip_bfloat16* __restrict__ ylo) {
  extern __shared__ char gsm[];
  float*  hl  = (float*)gsm;                            // [100][256]
  float2* cwL = (float2*)(gsm + 102400);                // [1600] (wk, loc-bits)
  int*    idsL = (int*)(gsm + 102400 + 12800);          // [100]
  float*  nvL  = (float*)(gsm + 102400 + 12800 + 400);  // [100]
  const int bin = blockIdx.x;
  const int gb0 = bin * 100;
  const int brow = (bin / NBINS) * NLOC;
  const int tid = threadIdx.x;
  const int p = tid >> 8, d = tid & 255;
  if (tid < BSZ) {
    idsL[tid] = order[gb0 + tid];
    nvL[tid] = normv[gb0 + tid];
  }
  __syncthreads();
  for (int t = tid; t < BSZ * KNN; t += 1024) {
    int lj = edstl[(size_t)gb0 * KNN + t];
    cwL[t] = make_float2(evals[(size_t)gb0 * KNN + t] * nvL[lj],
                         __int_as_float(lj));
  }
  for (int idx = tid; idx < BSZ * DH; idx += 1024) {
    int i = idx >> 8, dd = idx & 255;
    hl[i * 256 + dd] = hth[(size_t)(brow + idsL[i]) * DH + dd];
  }
  __syncthreads();
  size_t srow_n = (size_t)(brow + idsL[p]) * DH;
  float g_n = gate[srow_n + d], fh_n = fhet[srow_n + d];
  #pragma unroll 1
  for (int ii = 0; ii < 25; ii++) {
    const int i = ii * 4 + p;
    const size_t srow = srow_n;
    const float g = g_n, fh = fh_n;
    if (ii < 24) {
      srow_n = (size_t)(brow + idsL[i + 4]) * DH;
      g_n = gate[srow_n + d];
      fh_n = fhet[srow_n + d];
    }
    float acc = 0.f;
    #pragma unroll
    for (int k = 0; k < KNN; k++) {
      float2 cw = cwL[i * KNN + k];
      acc += cw.x * hl[__float_as_int(cw.y) * 256 + d];
    }
    float v = selu_f(g * (nvL[i] * acc) + (1.f - g) * fh);
    __hip_bfloat16 h, l;
    split_bf16(v, h, l);
    yhi[srow + d] = h;
    ylo[srow + d] = l;
  }
}

// ---------------- 9) out = z @ Wout + bout ----------------
template <int OW>
__global__ __launch_bounds__(256) void k_out(
    const float* __restrict__ Z, const float* __restrict__ W,
    const float* __restrict__ bias, float* __restrict__ out) {
  const int p0 = blockIdx.x * 32;
  __shared__ float zb[32][257];
  const int tid = threadIdx.x;
  for (int idx = tid; idx < 32 * DH; idx += 256) {
    int p = idx >> 8, d = idx & 255;
    zb[p][d] = Z[(size_t)(p0 + p) * DH + d];
  }
  __syncthreads();
  if (tid < 32 * OW) {
    int p = tid / OW, o = tid - (tid / OW) * OW;
    float acc = 0.f;
    #pragma unroll 4
    for (int d = 0; d < DH; d++) acc += zb[p][d] * W[d * OW + o];
    out[(size_t)(p0 + p) * OW + o] = acc + bias[o];
  }
}

// ---------------- host ----------------
extern "C" void kernel_launch(void* const* d_in, const int* in_sizes, int n_in,
                              void* d_out, int out_size, void* d_ws, size_t ws_size,
                              hipStream_t stream) {
  const float* X     = (const float*)d_in[0];
  const float* rot   = (const float*)d_in[1];
  const float* W_emb = (const float*)d_in[2];
  const float* b_emb = (const float*)d_in[3];
  const float* Wenc[2]  = {(const float*)d_in[4],  (const float*)d_in[14]};
  const float* benc[2]  = {(const float*)d_in[5],  (const float*)d_in[15]};
  const float* theta[2] = {(const float*)d_in[6],  (const float*)d_in[16]};
  const float* Wh[2]    = {(const float*)d_in[7],  (const float*)d_in[17]};
  const float* Wt[2]    = {(const float*)d_in[8],  (const float*)d_in[18]};
  const float* bt[2]    = {(const float*)d_in[9],  (const float*)d_in[19]};
  const float* Wdec[2]  = {(const float*)d_in[10], (const float*)d_in[20]};
  const float* bdec[2]  = {(const float*)d_in[11], (const float*)d_in[21]};
  const float* Wout[2]  = {(const float*)d_in[12], (const float*)d_in[22]};
  const float* bout[2]  = {(const float*)d_in[13], (const float*)d_in[23]};

  char* w = (char*)d_ws;
  double* emb   = (double*)(w + 0);
  float*  hth   = (float*)(w + 0);                  // alias emb (dead after k_dist)
  __hip_bfloat16* Bhi[2]  = {(__hip_bfloat16*)(w + OFF_BHI0),  (__hip_bfloat16*)(w + OFF_BHI1)};
  __hip_bfloat16* Blo[2]  = {(__hip_bfloat16*)(w + OFF_BLO0),  (__hip_bfloat16*)(w + OFF_BLO1)};
  __hip_bfloat16* Bdhi[2] = {(__hip_bfloat16*)(w + OFF_BDHI0), (__hip_bfloat16*)(w + OFF_BDHI1)};
  __hip_bfloat16* Bdlo[2] = {(__hip_bfloat16*)(w + OFF_BDLO0), (__hip_bfloat16*)(w + OFF_BDLO1)};
  float*  enc   = (float*)(w + OFF_ENC);
  int*    binid = (int*)(w + OFF_BIN);
  int*    order = (int*)(w + OFF_ORD);
  float*  normv = (float*)(w + OFF_NRM);            // sorted-position indexed
  float*  evals = (float*)(w + OFF_EVAL);
  int*    edstl = (int*)(w + OFF_EDST);             // local in-bin dst indices
  double* keys  = (double*)(w + OFF_KEYS);          // dead after k_topk
  double* na_u  = (double*)(w + OFF_NA);            // aliases fhet head
  __hip_bfloat16* Axhi = (__hip_bfloat16*)(w + OFF_AXHI);  // also yhi
  __hip_bfloat16* Axlo = (__hip_bfloat16*)(w + OFF_AXLO);  // also ylo
  float*  fhet  = (float*)(w + OFF_FHET);
  float*  gate  = (float*)(w + OFF_GATE);
  float*  zbuf  = (float*)(w + OFF_GATE);           // alias gate (dead after gather)
  float*  outp  = (float*)d_out;

  (void)hipFuncSetAttribute(reinterpret_cast<const void*>(k_gatherb),
                            hipFuncAttributeMaxDynamicSharedMemorySize, GAT_SMEM);
  (void)hipFuncSetAttribute(reinterpret_cast<const void*>(k_mfma<0>),
                            hipFuncAttributeMaxDynamicSharedMemorySize, MF_SMEM);
  (void)hipFuncSetAttribute(reinterpret_cast<const void*>(k_mfma<1>),
                            hipFuncAttributeMaxDynamicSharedMemorySize, MF_SMEM);

  k_enc_emb<<<NPTS / EPB, 256, 0, stream>>>(X, W_emb, b_emb, enc, emb, na_u);
  k_mul<<<NPTS / MULPTS, 512, 0, stream>>>(emb, rot, binid);
  k_sort<<<NB, 256, 0, stream>>>(binid, order);
  k_dist<<<NB * NBINS, 256, 0, stream>>>(emb, order, na_u, keys);
  k_topk<<<NPTS / 16, 256, 0, stream>>>(keys, evals, edstl, normv);
  k_cvt_w8<<<dim3(8, 8, 8), 256, 0, stream>>>(
      theta[0], Wh[0], Wt[0], Wdec[0], theta[1], Wh[1], Wt[1], Wdec[1],
      Bhi[0], Blo[0], Bdhi[0], Bdlo[0], Bhi[1], Blo[1], Bdhi[1], Bdlo[1]);

  for (int br = 0; br < 2; br++) {
    k_encmm<<<NPTS / XPB, 256, 0, stream>>>(enc, Wenc[br], benc[br], Axhi, Axlo);
    k_mfma<0><<<6 * 313, 256, MF_SMEM, stream>>>((const ushort*)Axhi, (const ushort*)Axlo,
                                                 (const ushort*)Bhi[br], (const ushort*)Blo[br],
                                                 bt[br], hth, fhet, gate);
    k_gatherb<<<NB * NBINS, 1024, GAT_SMEM, stream>>>(hth, fhet, gate, evals, edstl,
                                                      order, normv, Axhi, Axlo);
    k_mfma<1><<<2 * 313, 256, MF_SMEM, stream>>>((const ushort*)Axhi, (const ushort*)Axlo,
                                                 (const ushort*)Bdhi[br], (const ushort*)Bdlo[br],
                                                 bdec[br], zbuf, nullptr, nullptr);
    if (br == 0) k_out<8><<<NPTS / 32, 256, 0, stream>>>(zbuf, Wout[0], bout[0], outp);
    else         k_out<4><<<NPTS / 32, 256, 0, stream>>>(zbuf, Wout[1], bout[1], outp + (size_t)NPTS * 8);
  }
}